// Round 11
// baseline (429.599 us; speedup 1.0000x reference)
//
#include <hip/hip_runtime.h>
#include <math.h>

#define NN 100000
#define NE 1600000
#define DIN 128
#define NH 4
#define C1 32
#define C2 64
#define NEG 0.2f

#define SCAN_CHUNK 1024
#define NBLK ((NN + SCAN_CHUNK - 1) / SCAN_CHUNK)   // 98

#define NBUCK 8
#define BUCKN (NN / NBUCK)          // 12500 nodes per bucket
#define CAPB 300000                 // fixed bucket capacity (uniform dst -> ~200K each)
#define BIN_CHUNK 4096
#define NBINBLK ((NE + BIN_CHUNK - 1) / BIN_CHUNK)  // 391

__device__ __forceinline__ unsigned bf16rtn(float f) {
    unsigned b = __float_as_uint(f);
    return (b + 0x7FFFu + ((b >> 16) & 1u)) >> 16;
}
__device__ __forceinline__ unsigned pack2bf(float lo, float hi) {
    return bf16rtn(lo) | (bf16rtn(hi) << 16);
}

__global__ void k_setup(const float* __restrict__ We1, const float* __restrict__ ae1,
                        const float* __restrict__ We2, const float* __restrict__ ae2,
                        float* __restrict__ params) {
    __shared__ float sm[128];
    int t = threadIdx.x;
    sm[t] = We1[t] * ae1[t];
    __syncthreads();
    if (t < 4) {
        float s = 0.f;
        for (int c = 0; c < 32; c++) s += sm[t * 32 + c];
        params[2 + t] = s;            // ce1[h]
    }
    __syncthreads();
    if (t < 64) sm[t] = We2[t] * ae2[t];
    __syncthreads();
    if (t == 0) {
        float s = 0.f;
        for (int c = 0; c < 64; c++) s += sm[c];
        params[6] = s;                // ce2
        params[1] = params[0] / (float)NE;  // mean edge weight
    }
}

// ---- pass 1: bin edges into 8 dst-range buckets (fixed-capacity regions) ----
__global__ void k_binA(const int* __restrict__ srcI, const int* __restrict__ dstI,
                       const float* __restrict__ ew, int* __restrict__ bcur,
                       int* __restrict__ bdst, int2* __restrict__ bse,
                       float* __restrict__ params) {
    __shared__ int hcnt[NBUCK], hbase[NBUCK], hoff[NBUCK];
    int t = threadIdx.x;
    int e0 = blockIdx.x * BIN_CHUNK;
    if (t < NBUCK) hcnt[t] = 0;
    __syncthreads();
    for (int i = t; i < BIN_CHUNK; i += 256) {
        int e = e0 + i;
        if (e < NE) atomicAdd(&hcnt[dstI[e] / BUCKN], 1);
    }
    __syncthreads();
    if (t < NBUCK) { hbase[t] = atomicAdd(&bcur[t], hcnt[t]); hoff[t] = 0; }
    __syncthreads();
    float locw = 0.f;
    for (int i = t; i < BIN_CHUNK; i += 256) {
        int e = e0 + i;
        if (e < NE) {
            int d = dstI[e];
            float w = ew[e];
            locw += w;
            int b = d / BUCKN;
            int p = b * CAPB + hbase[b] + atomicAdd(&hoff[b], 1);
            bdst[p] = d;
            bse[p] = make_int2(srcI[e], __float_as_int(w));
        }
    }
    for (int o = 32; o > 0; o >>= 1) locw += __shfl_down(locw, o, 64);
    if ((t & 63) == 0) atomicAdd(&params[0], locw);
}

// ---- per-node degree histogram, XCD-local per bucket ----
__global__ void k_histB(const int* __restrict__ bdst, const int* __restrict__ bcur,
                        int* __restrict__ deg) {
    int b = blockIdx.x & (NBUCK - 1);
    int slice = blockIdx.x >> 3;
    int cnt = bcur[b];
    int lo = b * CAPB;
    int per = (cnt + 255) / 256;
    int s0 = lo + slice * per;
    int s1 = min(s0 + per, lo + cnt);
    for (int i = s0 + threadIdx.x; i < s1; i += 256)
        atomicAdd(&deg[bdst[i]], 1);
}

// block partial sums
__global__ void k_scanA(const int* __restrict__ deg, int* __restrict__ bsum) {
    __shared__ int ws[4];
    int b = blockIdx.x;
    int base = b * SCAN_CHUNK;
    int t = threadIdx.x;
    int s = 0;
    for (int i = t; i < SCAN_CHUNK; i += 256) {
        int idx = base + i;
        if (idx < NN) s += deg[idx];
    }
    for (int o = 32; o > 0; o >>= 1) s += __shfl_down(s, o, 64);
    int lane = t & 63, wid = t >> 6;
    if (lane == 0) ws[wid] = s;
    __syncthreads();
    if (t == 0) bsum[b] = ws[0] + ws[1] + ws[2] + ws[3];
}

__global__ void k_scanB(const int* __restrict__ bsum, int* __restrict__ bpre,
                        int* __restrict__ rowptr) {
    __shared__ int wtot[2];
    int t = threadIdx.x;
    int lane = t & 63, wid = t >> 6;
    int v = (t < NBLK) ? bsum[t] : 0;
    int inc = v;
    for (int o = 1; o < 64; o <<= 1) { int u = __shfl_up(inc, o, 64); if (lane >= o) inc += u; }
    if (lane == 63) wtot[wid] = inc;
    __syncthreads();
    if (wid == 1) inc += wtot[0];
    if (t < NBLK) bpre[t] = inc - v;          // exclusive prefix
    if (t == NBLK - 1) rowptr[NN] = inc;      // total == NE
}

__global__ void k_scanC(const int* __restrict__ deg, const int* __restrict__ bpre,
                        int* __restrict__ rowptr, int* __restrict__ cursor) {
    __shared__ int wtot[4];
    int b = blockIdx.x;
    int t = threadIdx.x;
    int lane = t & 63, wid = t >> 6;
    int idx0 = b * SCAN_CHUNK + t * 4;
    int d[4];
    int s = 0;
    #pragma unroll
    for (int j = 0; j < 4; j++) {
        int idx = idx0 + j;
        d[j] = (idx < NN) ? deg[idx] : 0;
        s += d[j];
    }
    int inc = s;
    for (int o = 1; o < 64; o <<= 1) { int u = __shfl_up(inc, o, 64); if (lane >= o) inc += u; }
    if (lane == 63) wtot[wid] = inc;
    __syncthreads();
    int add = bpre[b];
    for (int w = 0; w < wid; w++) add += wtot[w];
    int excl = inc - s + add;
    #pragma unroll
    for (int j = 0; j < 4; j++) {
        int idx = idx0 + j;
        if (idx < NN) { rowptr[idx] = excl; cursor[idx] = excl; }
        excl += d[j];
    }
}

// ---- pass 2: scatter within bucket; bucket = blockIdx.x & 7 tracks round-robin block->XCD ----
__global__ void k_binB(const int* __restrict__ bdst, const int2* __restrict__ bse,
                       const int* __restrict__ bcur, int* __restrict__ cursor,
                       int2* __restrict__ edge2) {
    int b = blockIdx.x & (NBUCK - 1);
    int slice = blockIdx.x >> 3;
    int cnt = bcur[b];
    int lo = b * CAPB;
    int per = (cnt + 255) / 256;
    int s0 = lo + slice * per;
    int s1 = min(s0 + per, lo + cnt);
    for (int i = s0 + threadIdx.x; i < s1; i += 256) {
        int d = bdst[i];
        int idx = atomicAdd(&cursor[d], 1);
        edge2[idx] = bse[i];
    }
}

// ---------------- Layer 1 GEMM: lane=row, wave=head(32 cols); x staged bf16 in LDS (16.6 KB) ----------------

__global__ void __launch_bounds__(256, 6)
k_gemm1(const float* __restrict__ x, const float* __restrict__ W1,
        const float* __restrict__ asv, const float* __restrict__ adv,
        unsigned* __restrict__ xs1b, float* __restrict__ as1, float* __restrict__ ad1) {
    __shared__ unsigned xt[64 * 65];   // [row][k2], 2 bf16 per dword, stride 65 (reads 2-way free)
    int t = threadIdx.x;
    int r0 = blockIdx.x * 64;
    for (int i = t; i < 2048; i += 256) {
        int row = i >> 5;
        int c4 = i & 31;
        float4 v = (r0 + row < NN) ? ((const float4*)x)[(size_t)(r0 + row) * 32 + c4]
                                   : make_float4(0.f, 0.f, 0.f, 0.f);
        xt[row * 65 + c4 * 2]     = pack2bf(v.x, v.y);
        xt[row * 65 + c4 * 2 + 1] = pack2bf(v.z, v.w);
    }
    __syncthreads();
    int wid = t >> 6, lane = t & 63;
    int row = r0 + lane;
    int c0 = __builtin_amdgcn_readfirstlane(wid * 32);
    float acc[32];
    #pragma unroll
    for (int c = 0; c < 32; c++) acc[c] = 0.f;
    const unsigned* xr = &xt[lane * 65];
    const float* wp = W1 + c0;
    #pragma unroll 4
    for (int k2 = 0; k2 < 64; k2++) {
        unsigned v = xr[k2];
        float x0 = __uint_as_float(v << 16);
        float x1 = __uint_as_float(v & 0xFFFF0000u);
        const float* w0 = wp + (2 * k2) * 128;
        const float* w1 = w0 + 128;
        #pragma unroll
        for (int c = 0; c < 32; c++) acc[c] += x0 * w0[c] + x1 * w1[c];
    }
    if (row < NN) {
        unsigned* orow = xs1b + (size_t)row * 64 + wid * 16;
        #pragma unroll
        for (int j = 0; j < 4; j++) {
            uint4 pk;
            pk.x = pack2bf(acc[8*j+0], acc[8*j+1]);
            pk.y = pack2bf(acc[8*j+2], acc[8*j+3]);
            pk.z = pack2bf(acc[8*j+4], acc[8*j+5]);
            pk.w = pack2bf(acc[8*j+6], acc[8*j+7]);
            *(uint4*)(orow + 4*j) = pk;
        }
        float ps = 0.f, pd = 0.f;
        #pragma unroll
        for (int c = 0; c < 32; c++) { ps += acc[c] * asv[c0 + c]; pd += acc[c] * adv[c0 + c]; }
        as1[row * 4 + wid] = ps;
        ad1[row * 4 + wid] = pd;
    }
}

// ---------------- Layer 1 aggregation: phase-split + MLP-batched gathers; h1 out bf16-packed ----------------

__global__ void k_agg1(const unsigned* __restrict__ xs1b, const float* __restrict__ as1,
                       const float* __restrict__ ad1, const int* __restrict__ rowptr,
                       const int2* __restrict__ edge2,
                       const float* __restrict__ params, const float* __restrict__ b1,
                       unsigned* __restrict__ h1b) {
    int wid = threadIdx.x >> 6, lane = threadIdx.x & 63;
    int n = blockIdx.x * 4 + wid;
    if (n >= NN) return;
    int h4 = lane & 3;          // head owned in phase 1
    int h  = lane >> 4;         // head mapped to channels in phase 2
    float ceP  = params[2 + h4];
    float adnP = ad1[n * 4 + h4];
    float meanw = params[1];
    float aself = as1[n * 4 + h] + ad1[n * 4 + h] + meanw * params[2 + h];
    aself = aself > 0.f ? aself : NEG * aself;
    float qs = __expf(aself);
    unsigned us = xs1b[(size_t)n * 64 + lane];
    float s  = qs;
    float ax = qs * __uint_as_float(us << 16);
    float ay = qs * __uint_as_float(us & 0xFFFF0000u);
    int lo = rowptr[n], hi = rowptr[n + 1];
    for (int base = lo; base < hi; base += 16) {
        int e = lane >> 2;
        int idx = base + e;
        int cx = 0;
        float q = 0.f;
        if (idx < hi) {
            int2 cv = edge2[idx];
            cx = cv.x;
            float a = as1[cx * 4 + h4] + adnP + __int_as_float(cv.y) * ceP;
            a = a > 0.f ? a : NEG * a;
            q = __expf(a);
        }
        int m = hi - base; if (m > 16) m = 16;
        int j = 0;
        for (; j + 8 <= m; j += 8) {
            int cj[8]; float qj[8]; unsigned vv[8];
            #pragma unroll
            for (int u = 0; u < 8; u++) {
                cj[u] = __shfl(cx, 4 * (j + u), 64);
                qj[u] = __shfl(q, 4 * (j + u) + h, 64);
            }
            #pragma unroll
            for (int u = 0; u < 8; u++) vv[u] = xs1b[(size_t)cj[u] * 64 + lane];
            #pragma unroll
            for (int u = 0; u < 8; u++) {
                s += qj[u];
                ax += qj[u] * __uint_as_float(vv[u] << 16);
                ay += qj[u] * __uint_as_float(vv[u] & 0xFFFF0000u);
            }
        }
        for (; j < m; j++) {
            int cj = __shfl(cx, 4 * j, 64);
            float qj = __shfl(q, 4 * j + h, 64);
            unsigned u = xs1b[(size_t)cj * 64 + lane];
            s += qj;
            ax += qj * __uint_as_float(u << 16);
            ay += qj * __uint_as_float(u & 0xFFFF0000u);
        }
    }
    float inv = 1.0f / (s + 1e-16f);
    float o0 = ax * inv + b1[2 * lane];
    float o1 = ay * inv + b1[2 * lane + 1];
    o0 = o0 > 0.f ? o0 : (__expf(o0) - 1.0f);   // ELU
    o1 = o1 > 0.f ? o1 : (__expf(o1) - 1.0f);
    h1b[(size_t)n * 64 + lane] = pack2bf(o0, o1);
}

// ---------------- Layer 2 GEMM: lane=row, wave=16 cols; h1 (bf16-packed) staged in LDS ----------------

__global__ void __launch_bounds__(256, 6)
k_gemm2(const unsigned* __restrict__ h1b, const float* __restrict__ W2,
        const float* __restrict__ asv, const float* __restrict__ adv,
        unsigned* __restrict__ xs2b, float* __restrict__ as2, float* __restrict__ ad2) {
    __shared__ unsigned xt[64 * 65];     // 16.6 KB
    __shared__ float pp[2][4][64];       // cross-wave alpha partials (2 KB)
    int t = threadIdx.x;
    int r0 = blockIdx.x * 64;
    for (int i = t; i < 1024; i += 256) {
        int row = i >> 4;
        int q = i & 15;
        uint4 v = (r0 + row < NN) ? ((const uint4*)h1b)[(size_t)(r0 + row) * 16 + q]
                                  : make_uint4(0u, 0u, 0u, 0u);
        unsigned* dst = &xt[row * 65 + q * 4];
        dst[0] = v.x; dst[1] = v.y; dst[2] = v.z; dst[3] = v.w;
    }
    __syncthreads();
    int wid = t >> 6, lane = t & 63;
    int row = r0 + lane;
    int c0 = __builtin_amdgcn_readfirstlane(wid * 16);
    float acc[16];
    #pragma unroll
    for (int c = 0; c < 16; c++) acc[c] = 0.f;
    const unsigned* xr = &xt[lane * 65];
    const float* wp = W2 + c0;
    #pragma unroll 4
    for (int k2 = 0; k2 < 64; k2++) {
        unsigned v = xr[k2];
        float x0 = __uint_as_float(v << 16);
        float x1 = __uint_as_float(v & 0xFFFF0000u);
        const float* w0 = wp + (2 * k2) * 64;
        const float* w1 = w0 + 64;
        #pragma unroll
        for (int c = 0; c < 16; c++) acc[c] += x0 * w0[c] + x1 * w1[c];
    }
    float ps = 0.f, pd = 0.f;
    #pragma unroll
    for (int c = 0; c < 16; c++) { ps += acc[c] * asv[c0 + c]; pd += acc[c] * adv[c0 + c]; }
    pp[0][wid][lane] = ps;
    pp[1][wid][lane] = pd;
    if (row < NN) {
        unsigned* orow = xs2b + (size_t)row * 32 + wid * 8;
        #pragma unroll
        for (int j = 0; j < 2; j++) {
            uint4 pk;
            pk.x = pack2bf(acc[8*j+0], acc[8*j+1]);
            pk.y = pack2bf(acc[8*j+2], acc[8*j+3]);
            pk.z = pack2bf(acc[8*j+4], acc[8*j+5]);
            pk.w = pack2bf(acc[8*j+6], acc[8*j+7]);
            *(uint4*)(orow + 4*j) = pk;
        }
    }
    __syncthreads();
    if (wid == 0 && row < NN) {
        as2[row] = pp[0][0][lane] + pp[0][1][lane] + pp[0][2][lane] + pp[0][3][lane];
        ad2[row] = pp[1][0][lane] + pp[1][1][lane] + pp[1][2][lane] + pp[1][3][lane];
    }
}

// ---------------- Layer 2 aggregation: phase-split + MLP-batched gathers ----------------

__global__ void k_agg2(const unsigned short* __restrict__ xs2h, const float* __restrict__ as2,
                       const float* __restrict__ ad2, const int* __restrict__ rowptr,
                       const int2* __restrict__ edge2,
                       const float* __restrict__ params, const float* __restrict__ b2,
                       float* __restrict__ out) {
    int wid = threadIdx.x >> 6, lane = threadIdx.x & 63;
    int n = blockIdx.x * 4 + wid;
    if (n >= NN) return;
    float ce = params[6];
    float meanw = params[1];
    float adn = ad2[n];
    float aself = as2[n] + adn + meanw * ce;
    aself = aself > 0.f ? aself : NEG * aself;
    float qs = __expf(aself);
    float s = qs;
    float ac = qs * __uint_as_float(((unsigned)xs2h[(size_t)n * 64 + lane]) << 16);
    int lo = rowptr[n], hi = rowptr[n + 1];
    for (int base = lo; base < hi; base += 64) {
        int idx = base + lane;
        int cx = 0;
        float q = 0.f;
        if (idx < hi) {
            int2 cv = edge2[idx];
            cx = cv.x;
            float a = as2[cx] + adn + __int_as_float(cv.y) * ce;
            a = a > 0.f ? a : NEG * a;
            q = __expf(a);
        }
        int m = hi - base; if (m > 64) m = 64;
        int j = 0;
        for (; j + 8 <= m; j += 8) {
            int cj[8]; float qj[8]; unsigned short vv[8];
            #pragma unroll
            for (int u = 0; u < 8; u++) {
                cj[u] = __shfl(cx, j + u, 64);
                qj[u] = __shfl(q, j + u, 64);
            }
            #pragma unroll
            for (int u = 0; u < 8; u++) vv[u] = xs2h[(size_t)cj[u] * 64 + lane];
            #pragma unroll
            for (int u = 0; u < 8; u++) {
                s += qj[u];
                ac += qj[u] * __uint_as_float(((unsigned)vv[u]) << 16);
            }
        }
        for (; j < m; j++) {
            int cj = __shfl(cx, j, 64);
            float qj = __shfl(q, j, 64);
            float v = __uint_as_float(((unsigned)xs2h[(size_t)cj * 64 + lane]) << 16);
            s += qj;
            ac += qj * v;
        }
    }
    out[(size_t)n * 64 + lane] = ac / (s + 1e-16f) + b2[lane];
}

extern "C" void kernel_launch(void* const* d_in, const int* in_sizes, int n_in,
                              void* d_out, int out_size, void* d_ws, size_t ws_size,
                              hipStream_t stream) {
    const float* x    = (const float*)d_in[0];
    const int*   ei   = (const int*)d_in[1];
    const float* ew   = (const float*)d_in[2];
    const float* W1   = (const float*)d_in[3];
    const float* as1v = (const float*)d_in[4];
    const float* ad1v = (const float*)d_in[5];
    const float* ae1v = (const float*)d_in[6];
    const float* We1  = (const float*)d_in[7];
    const float* b1   = (const float*)d_in[8];
    const float* W2   = (const float*)d_in[9];
    const float* as2v = (const float*)d_in[10];
    const float* ad2v = (const float*)d_in[11];
    const float* ae2v = (const float*)d_in[12];
    const float* We2  = (const float*)d_in[13];
    const float* b2   = (const float*)d_in[14];
    const int* srcI = ei;
    const int* dstI = ei + NE;

    float* wsf = (float*)d_ws;
    size_t off = 0;
    auto alloc = [&](size_t nelts) { float* p = wsf + off; off += (nelts + 63) & ~(size_t)63; return p; };
    float*    params = alloc(64);
    int*      deg    = (int*)alloc(NN);            // padded to 100032
    int*      bcur   = (int*)alloc(64);
    int*      rowptr = (int*)alloc(NN + 1);
    int*      cursor = (int*)alloc(NN);
    int*      bsum   = (int*)alloc(NBLK);
    int*      bpre   = (int*)alloc(NBLK);
    size_t    binsOff = off;
    int*      bdst   = (int*)alloc((size_t)NBUCK * CAPB);        // 2.4M ints
    int2*     bse    = (int2*)alloc((size_t)NBUCK * CAPB * 2);   // 4.8M ints
    int2*     edge2  = (int2*)alloc((size_t)NE * 2);
    float*    as1    = alloc(NN * 4);
    float*    ad1    = alloc(NN * 4);
    unsigned* h1b    = (unsigned*)alloc((size_t)NN * 64);        // bf16-packed h1 [N][128]
    // xs1b overlays the bin region (bdst+bse = 7.2M words >= 6.4M; bins dead before gemm1)
    unsigned* xs1b   = (unsigned*)(wsf + binsOff);
    unsigned* xs2b   = xs1b;
    float*    as2 = as1;
    float*    ad2 = ad1;

    // zero params + deg + bcur (contiguous at ws start)
    hipMemsetAsync(d_ws, 0, (64 + 100032 + 64) * sizeof(float), stream);

    k_binA <<<NBINBLK, 256, 0, stream>>>(srcI, dstI, ew, bcur, bdst, bse, params);
    k_histB<<<2048, 256, 0, stream>>>(bdst, bcur, deg);
    k_scanA<<<NBLK, 256, 0, stream>>>(deg, bsum);
    k_scanB<<<1, 128, 0, stream>>>(bsum, bpre, rowptr);
    k_scanC<<<NBLK, 256, 0, stream>>>(deg, bpre, rowptr, cursor);
    k_binB <<<2048, 256, 0, stream>>>(bdst, bse, bcur, cursor, edge2);
    k_setup<<<1, 128, 0, stream>>>(We1, ae1v, We2, ae2v, params);
    k_gemm1<<<(NN + 63) / 64, 256, 0, stream>>>(x, W1, as1v, ad1v, xs1b, as1, ad1);
    k_agg1 <<<25000, 256, 0, stream>>>(xs1b, as1, ad1, rowptr, edge2, params, b1, h1b);
    k_gemm2<<<(NN + 63) / 64, 256, 0, stream>>>(h1b, W2, as2v, ad2v, xs2b, as2, ad2);
    k_agg2 <<<25000, 256, 0, stream>>>((const unsigned short*)xs2b, as2, ad2, rowptr, edge2, params, b2, (float*)d_out);
}

// Round 12
// 368.047 us; speedup vs baseline: 1.1672x; 1.1672x over previous
//
#include <hip/hip_runtime.h>
#include <math.h>

#define NN 100000
#define NE 1600000
#define DIN 128
#define NH 4
#define C1 32
#define C2 64
#define NEG 0.2f

#define SCAN_CHUNK 1024
#define NBLK ((NN + SCAN_CHUNK - 1) / SCAN_CHUNK)   // 98

#define NBUCK 8
#define BUCKN (NN / NBUCK)          // 12500 nodes per bucket
#define CAPB 300000                 // fixed bucket capacity (uniform dst -> ~200K each)
#define BIN_CHUNK 4096
#define NBINBLK ((NE + BIN_CHUNK - 1) / BIN_CHUNK)  // 391

typedef __attribute__((ext_vector_type(8))) short bf16x8;
typedef __attribute__((ext_vector_type(4))) float f32x4;

__device__ __forceinline__ unsigned bf16rtn(float f) {
    unsigned b = __float_as_uint(f);
    return (b + 0x7FFFu + ((b >> 16) & 1u)) >> 16;
}
__device__ __forceinline__ unsigned pack2bf(float lo, float hi) {
    return bf16rtn(lo) | (bf16rtn(hi) << 16);
}

__global__ void k_setup(const float* __restrict__ We1, const float* __restrict__ ae1,
                        const float* __restrict__ We2, const float* __restrict__ ae2,
                        float* __restrict__ params) {
    __shared__ float sm[128];
    int t = threadIdx.x;
    sm[t] = We1[t] * ae1[t];
    __syncthreads();
    if (t < 4) {
        float s = 0.f;
        for (int c = 0; c < 32; c++) s += sm[t * 32 + c];
        params[2 + t] = s;            // ce1[h]
    }
    __syncthreads();
    if (t < 64) sm[t] = We2[t] * ae2[t];
    __syncthreads();
    if (t == 0) {
        float s = 0.f;
        for (int c = 0; c < 64; c++) s += sm[c];
        params[6] = s;                // ce2
        params[1] = params[0] / (float)NE;  // mean edge weight
    }
}

// ---- pre-pack W1/W2 into MFMA B-fragment-linear bf16 buffers ----
// B-frag layout (16x16x32): col = lane&15, k = (lane>>4)*8 + e
__global__ void k_wprep(const float* __restrict__ W1, const float* __restrict__ W2,
                        uint4* __restrict__ wfrag1, uint4* __restrict__ wfrag2) {
    int t = blockIdx.x * 256 + threadIdx.x;
    if (t < 2048) {                       // W1: 8 col-tiles x 4 k-chunks x 64 lanes
        int f = t >> 6, l = t & 63;
        int n = f & 7, kc = f >> 3;
        int col = n * 16 + (l & 15);
        int kb = kc * 32 + (l >> 4) * 8;
        const float* p = W1 + (size_t)kb * 128 + col;
        uint4 pk;
        pk.x = pack2bf(p[0], p[128]);
        pk.y = pack2bf(p[256], p[384]);
        pk.z = pack2bf(p[512], p[640]);
        pk.w = pack2bf(p[768], p[896]);
        wfrag1[t] = pk;
    } else if (t < 3072) {                // W2: 4 col-tiles x 4 k-chunks x 64 lanes
        int s = t - 2048;
        int f = s >> 6, l = s & 63;
        int n = f & 3, kc = f >> 2;
        int col = n * 16 + (l & 15);
        int kb = kc * 32 + (l >> 4) * 8;
        const float* p = W2 + (size_t)kb * 64 + col;
        uint4 pk;
        pk.x = pack2bf(p[0], p[64]);
        pk.y = pack2bf(p[128], p[192]);
        pk.z = pack2bf(p[256], p[320]);
        pk.w = pack2bf(p[384], p[448]);
        wfrag2[s] = pk;
    }
}

// ---- pass 1: bin edges into 8 dst-range buckets (fixed-capacity regions) ----
__global__ void k_binA(const int* __restrict__ srcI, const int* __restrict__ dstI,
                       const float* __restrict__ ew, int* __restrict__ bcur,
                       int* __restrict__ bdst, int2* __restrict__ bse,
                       float* __restrict__ params) {
    __shared__ int hcnt[NBUCK], hbase[NBUCK], hoff[NBUCK];
    int t = threadIdx.x;
    int e0 = blockIdx.x * BIN_CHUNK;
    if (t < NBUCK) hcnt[t] = 0;
    __syncthreads();
    for (int i = t; i < BIN_CHUNK; i += 256) {
        int e = e0 + i;
        if (e < NE) atomicAdd(&hcnt[dstI[e] / BUCKN], 1);
    }
    __syncthreads();
    if (t < NBUCK) { hbase[t] = atomicAdd(&bcur[t], hcnt[t]); hoff[t] = 0; }
    __syncthreads();
    float locw = 0.f;
    for (int i = t; i < BIN_CHUNK; i += 256) {
        int e = e0 + i;
        if (e < NE) {
            int d = dstI[e];
            float w = ew[e];
            locw += w;
            int b = d / BUCKN;
            int p = b * CAPB + hbase[b] + atomicAdd(&hoff[b], 1);
            bdst[p] = d;
            bse[p] = make_int2(srcI[e], __float_as_int(w));
        }
    }
    for (int o = 32; o > 0; o >>= 1) locw += __shfl_down(locw, o, 64);
    if ((t & 63) == 0) atomicAdd(&params[0], locw);
}

// ---- per-node degree histogram, XCD-local per bucket ----
__global__ void k_histB(const int* __restrict__ bdst, const int* __restrict__ bcur,
                        int* __restrict__ deg) {
    int b = blockIdx.x & (NBUCK - 1);
    int slice = blockIdx.x >> 3;
    int cnt = bcur[b];
    int lo = b * CAPB;
    int per = (cnt + 255) / 256;
    int s0 = lo + slice * per;
    int s1 = min(s0 + per, lo + cnt);
    for (int i = s0 + threadIdx.x; i < s1; i += 256)
        atomicAdd(&deg[bdst[i]], 1);
}

// block partial sums
__global__ void k_scanA(const int* __restrict__ deg, int* __restrict__ bsum) {
    __shared__ int ws[4];
    int b = blockIdx.x;
    int base = b * SCAN_CHUNK;
    int t = threadIdx.x;
    int s = 0;
    for (int i = t; i < SCAN_CHUNK; i += 256) {
        int idx = base + i;
        if (idx < NN) s += deg[idx];
    }
    for (int o = 32; o > 0; o >>= 1) s += __shfl_down(s, o, 64);
    int lane = t & 63, wid = t >> 6;
    if (lane == 0) ws[wid] = s;
    __syncthreads();
    if (t == 0) bsum[b] = ws[0] + ws[1] + ws[2] + ws[3];
}

__global__ void k_scanB(const int* __restrict__ bsum, int* __restrict__ bpre,
                        int* __restrict__ rowptr) {
    __shared__ int wtot[2];
    int t = threadIdx.x;
    int lane = t & 63, wid = t >> 6;
    int v = (t < NBLK) ? bsum[t] : 0;
    int inc = v;
    for (int o = 1; o < 64; o <<= 1) { int u = __shfl_up(inc, o, 64); if (lane >= o) inc += u; }
    if (lane == 63) wtot[wid] = inc;
    __syncthreads();
    if (wid == 1) inc += wtot[0];
    if (t < NBLK) bpre[t] = inc - v;          // exclusive prefix
    if (t == NBLK - 1) rowptr[NN] = inc;      // total == NE
}

__global__ void k_scanC(const int* __restrict__ deg, const int* __restrict__ bpre,
                        int* __restrict__ rowptr, int* __restrict__ cursor) {
    __shared__ int wtot[4];
    int b = blockIdx.x;
    int t = threadIdx.x;
    int lane = t & 63, wid = t >> 6;
    int idx0 = b * SCAN_CHUNK + t * 4;
    int d[4];
    int s = 0;
    #pragma unroll
    for (int j = 0; j < 4; j++) {
        int idx = idx0 + j;
        d[j] = (idx < NN) ? deg[idx] : 0;
        s += d[j];
    }
    int inc = s;
    for (int o = 1; o < 64; o <<= 1) { int u = __shfl_up(inc, o, 64); if (lane >= o) inc += u; }
    if (lane == 63) wtot[wid] = inc;
    __syncthreads();
    int add = bpre[b];
    for (int w = 0; w < wid; w++) add += wtot[w];
    int excl = inc - s + add;
    #pragma unroll
    for (int j = 0; j < 4; j++) {
        int idx = idx0 + j;
        if (idx < NN) { rowptr[idx] = excl; cursor[idx] = excl; }
        excl += d[j];
    }
}

// ---- pass 2: scatter within bucket; bucket = blockIdx.x & 7 tracks round-robin block->XCD ----
__global__ void k_binB(const int* __restrict__ bdst, const int2* __restrict__ bse,
                       const int* __restrict__ bcur, int* __restrict__ cursor,
                       int2* __restrict__ edge2) {
    int b = blockIdx.x & (NBUCK - 1);
    int slice = blockIdx.x >> 3;
    int cnt = bcur[b];
    int lo = b * CAPB;
    int per = (cnt + 255) / 256;
    int s0 = lo + slice * per;
    int s1 = min(s0 + per, lo + cnt);
    for (int i = s0 + threadIdx.x; i < s1; i += 256) {
        int d = bdst[i];
        int idx = atomicAdd(&cursor[d], 1);
        edge2[idx] = bse[i];
    }
}

// ---------------- Layer 1 GEMM via MFMA: 64 rows/block, 4 waves x 16 rows ----------------

__global__ void __launch_bounds__(256, 4)
k_gemm1(const float* __restrict__ x, const uint4* __restrict__ wfrag1,
        const float* __restrict__ asv, const float* __restrict__ adv,
        unsigned* __restrict__ xs1b, float* __restrict__ as1, float* __restrict__ ad1) {
    __shared__ uint4 smem[2112];   // 33.8 KB: W frags (2048 uint4), reused as epilogue fp32 buf
    int t = threadIdx.x;
    for (int i = t; i < 2048; i += 256) smem[i] = wfrag1[i];
    __syncthreads();
    int wid = t >> 6, lane = t & 63;
    int r0 = blockIdx.x * 64 + wid * 16;
    int rowA = r0 + (lane & 15);
    int kb = (lane >> 4) * 8;
    bf16x8 afr[4];
    if (rowA < NN) {
        const float* xr = x + (size_t)rowA * 128 + kb;
        #pragma unroll
        for (int kc = 0; kc < 4; kc++) {
            float4 u0 = *(const float4*)(xr + kc * 32);
            float4 u1 = *(const float4*)(xr + kc * 32 + 4);
            uint4 p = make_uint4(pack2bf(u0.x, u0.y), pack2bf(u0.z, u0.w),
                                 pack2bf(u1.x, u1.y), pack2bf(u1.z, u1.w));
            afr[kc] = *(bf16x8*)&p;
        }
    } else {
        uint4 z = make_uint4(0u, 0u, 0u, 0u);
        #pragma unroll
        for (int kc = 0; kc < 4; kc++) afr[kc] = *(bf16x8*)&z;
    }
    f32x4 acc[8];
    #pragma unroll
    for (int n = 0; n < 8; n++) acc[n] = (f32x4){0.f, 0.f, 0.f, 0.f};
    #pragma unroll
    for (int kc = 0; kc < 4; kc++) {
        #pragma unroll
        for (int n = 0; n < 8; n++) {
            uint4 bw = smem[(kc * 8 + n) * 64 + lane];
            acc[n] = __builtin_amdgcn_mfma_f32_16x16x32_bf16(afr[kc], *(bf16x8*)&bw, acc[n], 0, 0, 0);
        }
    }
    __syncthreads();                      // all waves done reading W frags
    float* ef = (float*)smem + wid * 2112;  // 16 rows x 132 (col' = (col>>5)*33 + (col&31))
    #pragma unroll
    for (int n = 0; n < 8; n++) {
        #pragma unroll
        for (int r = 0; r < 4; r++) {
            int rw = (lane >> 4) * 4 + r;
            int col = n * 16 + (lane & 15);
            ef[rw * 132 + (col >> 5) * 33 + (col & 31)] = acc[n][r];
        }
    }
    __syncthreads();
    int rw = lane >> 2, head = lane & 3;
    int row = r0 + rw;
    if (row < NN) {
        const float* rb = ef + rw * 132 + head * 33;
        const float* av = asv + head * 32;
        const float* dv = adv + head * 32;
        unsigned* orow = xs1b + (size_t)row * 64 + head * 16;
        float ps = 0.f, pd = 0.f;
        #pragma unroll
        for (int j = 0; j < 4; j++) {
            float v[8];
            #pragma unroll
            for (int e = 0; e < 8; e++) {
                v[e] = rb[8 * j + e];
                ps += v[e] * av[8 * j + e];
                pd += v[e] * dv[8 * j + e];
            }
            uint4 pk = make_uint4(pack2bf(v[0], v[1]), pack2bf(v[2], v[3]),
                                  pack2bf(v[4], v[5]), pack2bf(v[6], v[7]));
            *(uint4*)(orow + 4 * j) = pk;
        }
        as1[row * 4 + head] = ps;
        ad1[row * 4 + head] = pd;
    }
}

// ---------------- Layer 1 aggregation: phase-split + MLP-batched gathers; h1 out bf16-packed ----------------

__global__ void k_agg1(const unsigned* __restrict__ xs1b, const float* __restrict__ as1,
                       const float* __restrict__ ad1, const int* __restrict__ rowptr,
                       const int2* __restrict__ edge2,
                       const float* __restrict__ params, const float* __restrict__ b1,
                       unsigned* __restrict__ h1b) {
    int wid = threadIdx.x >> 6, lane = threadIdx.x & 63;
    int n = blockIdx.x * 4 + wid;
    if (n >= NN) return;
    int h4 = lane & 3;          // head owned in phase 1
    int h  = lane >> 4;         // head mapped to channels in phase 2
    float ceP  = params[2 + h4];
    float adnP = ad1[n * 4 + h4];
    float meanw = params[1];
    float aself = as1[n * 4 + h] + ad1[n * 4 + h] + meanw * params[2 + h];
    aself = aself > 0.f ? aself : NEG * aself;
    float qs = __expf(aself);
    unsigned us = xs1b[(size_t)n * 64 + lane];
    float s  = qs;
    float ax = qs * __uint_as_float(us << 16);
    float ay = qs * __uint_as_float(us & 0xFFFF0000u);
    int lo = rowptr[n], hi = rowptr[n + 1];
    for (int base = lo; base < hi; base += 16) {
        int e = lane >> 2;
        int idx = base + e;
        int cx = 0;
        float q = 0.f;
        if (idx < hi) {
            int2 cv = edge2[idx];
            cx = cv.x;
            float a = as1[cx * 4 + h4] + adnP + __int_as_float(cv.y) * ceP;
            a = a > 0.f ? a : NEG * a;
            q = __expf(a);
        }
        int m = hi - base; if (m > 16) m = 16;
        int j = 0;
        for (; j + 8 <= m; j += 8) {
            int cj[8]; float qj[8]; unsigned vv[8];
            #pragma unroll
            for (int u = 0; u < 8; u++) {
                cj[u] = __shfl(cx, 4 * (j + u), 64);
                qj[u] = __shfl(q, 4 * (j + u) + h, 64);
            }
            #pragma unroll
            for (int u = 0; u < 8; u++) vv[u] = xs1b[(size_t)cj[u] * 64 + lane];
            #pragma unroll
            for (int u = 0; u < 8; u++) {
                s += qj[u];
                ax += qj[u] * __uint_as_float(vv[u] << 16);
                ay += qj[u] * __uint_as_float(vv[u] & 0xFFFF0000u);
            }
        }
        for (; j < m; j++) {
            int cj = __shfl(cx, 4 * j, 64);
            float qj = __shfl(q, 4 * j + h, 64);
            unsigned u = xs1b[(size_t)cj * 64 + lane];
            s += qj;
            ax += qj * __uint_as_float(u << 16);
            ay += qj * __uint_as_float(u & 0xFFFF0000u);
        }
    }
    float inv = 1.0f / (s + 1e-16f);
    float o0 = ax * inv + b1[2 * lane];
    float o1 = ay * inv + b1[2 * lane + 1];
    o0 = o0 > 0.f ? o0 : (__expf(o0) - 1.0f);   // ELU
    o1 = o1 > 0.f ? o1 : (__expf(o1) - 1.0f);
    h1b[(size_t)n * 64 + lane] = pack2bf(o0, o1);
}

// ---------------- Layer 2 GEMM via MFMA: A direct from bf16-packed h1b ----------------

__global__ void __launch_bounds__(256, 6)
k_gemm2(const unsigned* __restrict__ h1b, const uint4* __restrict__ wfrag2,
        const float* __restrict__ asv, const float* __restrict__ adv,
        unsigned* __restrict__ xs2b, float* __restrict__ as2, float* __restrict__ ad2) {
    __shared__ uint4 smem[1056];   // 16.9 KB: W frags (1024 uint4), reused as epilogue buf
    int t = threadIdx.x;
    for (int i = t; i < 1024; i += 256) smem[i] = wfrag2[i];
    __syncthreads();
    int wid = t >> 6, lane = t & 63;
    int r0 = blockIdx.x * 64 + wid * 16;
    int rowA = r0 + (lane & 15);
    bf16x8 afr[4];
    if (rowA < NN) {
        const uint4* hr = (const uint4*)(h1b + (size_t)rowA * 64);
        #pragma unroll
        for (int kc = 0; kc < 4; kc++) {
            uint4 p = hr[kc * 4 + (lane >> 4)];
            afr[kc] = *(bf16x8*)&p;
        }
    } else {
        uint4 z = make_uint4(0u, 0u, 0u, 0u);
        #pragma unroll
        for (int kc = 0; kc < 4; kc++) afr[kc] = *(bf16x8*)&z;
    }
    f32x4 acc[4];
    #pragma unroll
    for (int n = 0; n < 4; n++) acc[n] = (f32x4){0.f, 0.f, 0.f, 0.f};
    #pragma unroll
    for (int kc = 0; kc < 4; kc++) {
        #pragma unroll
        for (int n = 0; n < 4; n++) {
            uint4 bw = smem[(kc * 4 + n) * 64 + lane];
            acc[n] = __builtin_amdgcn_mfma_f32_16x16x32_bf16(afr[kc], *(bf16x8*)&bw, acc[n], 0, 0, 0);
        }
    }
    __syncthreads();
    float* ef = (float*)smem + wid * 1056;  // 16 rows x 66
    #pragma unroll
    for (int n = 0; n < 4; n++) {
        #pragma unroll
        for (int r = 0; r < 4; r++) {
            int rw = (lane >> 4) * 4 + r;
            int col = n * 16 + (lane & 15);
            ef[rw * 66 + (col >> 5) * 33 + (col & 31)] = acc[n][r];
        }
    }
    __syncthreads();
    int rw = lane >> 2, q = lane & 3;
    int row = r0 + rw;
    const float* rb = ef + rw * 66 + (q >> 1) * 33 + (q & 1) * 16;
    const float* av = asv + q * 16;
    const float* dv = adv + q * 16;
    float ps = 0.f, pd = 0.f;
    unsigned pk[4];
    #pragma unroll
    for (int j = 0; j < 2; j++) {
        float v[8];
        #pragma unroll
        for (int e = 0; e < 8; e++) {
            v[e] = rb[8 * j + e];
            ps += v[e] * av[8 * j + e];
            pd += v[e] * dv[8 * j + e];
        }
        pk[0] = pack2bf(v[0], v[1]); pk[1] = pack2bf(v[2], v[3]);
        pk[2] = pack2bf(v[4], v[5]); pk[3] = pack2bf(v[6], v[7]);
        if (row < NN)
            *(uint4*)(xs2b + (size_t)row * 32 + q * 8 + 4 * j) = make_uint4(pk[0], pk[1], pk[2], pk[3]);
    }
    ps += __shfl_xor(ps, 1, 64); ps += __shfl_xor(ps, 2, 64);
    pd += __shfl_xor(pd, 1, 64); pd += __shfl_xor(pd, 2, 64);
    if (q == 0 && row < NN) { as2[row] = ps; ad2[row] = pd; }
}

// ---------------- Layer 2 aggregation: phase-split + MLP-batched gathers ----------------

__global__ void k_agg2(const unsigned short* __restrict__ xs2h, const float* __restrict__ as2,
                       const float* __restrict__ ad2, const int* __restrict__ rowptr,
                       const int2* __restrict__ edge2,
                       const float* __restrict__ params, const float* __restrict__ b2,
                       float* __restrict__ out) {
    int wid = threadIdx.x >> 6, lane = threadIdx.x & 63;
    int n = blockIdx.x * 4 + wid;
    if (n >= NN) return;
    float ce = params[6];
    float meanw = params[1];
    float adn = ad2[n];
    float aself = as2[n] + adn + meanw * ce;
    aself = aself > 0.f ? aself : NEG * aself;
    float qs = __expf(aself);
    float s = qs;
    float ac = qs * __uint_as_float(((unsigned)xs2h[(size_t)n * 64 + lane]) << 16);
    int lo = rowptr[n], hi = rowptr[n + 1];
    for (int base = lo; base < hi; base += 64) {
        int idx = base + lane;
        int cx = 0;
        float q = 0.f;
        if (idx < hi) {
            int2 cv = edge2[idx];
            cx = cv.x;
            float a = as2[cx] + adn + __int_as_float(cv.y) * ce;
            a = a > 0.f ? a : NEG * a;
            q = __expf(a);
        }
        int m = hi - base; if (m > 64) m = 64;
        int j = 0;
        for (; j + 8 <= m; j += 8) {
            int cj[8]; float qj[8]; unsigned short vv[8];
            #pragma unroll
            for (int u = 0; u < 8; u++) {
                cj[u] = __shfl(cx, j + u, 64);
                qj[u] = __shfl(q, j + u, 64);
            }
            #pragma unroll
            for (int u = 0; u < 8; u++) vv[u] = xs2h[(size_t)cj[u] * 64 + lane];
            #pragma unroll
            for (int u = 0; u < 8; u++) {
                s += qj[u];
                ac += qj[u] * __uint_as_float(((unsigned)vv[u]) << 16);
            }
        }
        for (; j < m; j++) {
            int cj = __shfl(cx, j, 64);
            float qj = __shfl(q, j, 64);
            float v = __uint_as_float(((unsigned)xs2h[(size_t)cj * 64 + lane]) << 16);
            s += qj;
            ac += qj * v;
        }
    }
    out[(size_t)n * 64 + lane] = ac / (s + 1e-16f) + b2[lane];
}

extern "C" void kernel_launch(void* const* d_in, const int* in_sizes, int n_in,
                              void* d_out, int out_size, void* d_ws, size_t ws_size,
                              hipStream_t stream) {
    const float* x    = (const float*)d_in[0];
    const int*   ei   = (const int*)d_in[1];
    const float* ew   = (const float*)d_in[2];
    const float* W1   = (const float*)d_in[3];
    const float* as1v = (const float*)d_in[4];
    const float* ad1v = (const float*)d_in[5];
    const float* ae1v = (const float*)d_in[6];
    const float* We1  = (const float*)d_in[7];
    const float* b1   = (const float*)d_in[8];
    const float* W2   = (const float*)d_in[9];
    const float* as2v = (const float*)d_in[10];
    const float* ad2v = (const float*)d_in[11];
    const float* ae2v = (const float*)d_in[12];
    const float* We2  = (const float*)d_in[13];
    const float* b2   = (const float*)d_in[14];
    const int* srcI = ei;
    const int* dstI = ei + NE;

    float* wsf = (float*)d_ws;
    size_t off = 0;
    auto alloc = [&](size_t nelts) { float* p = wsf + off; off += (nelts + 63) & ~(size_t)63; return p; };
    float*    params = alloc(64);
    int*      deg    = (int*)alloc(NN);            // padded to 100032
    int*      bcur   = (int*)alloc(64);
    int*      rowptr = (int*)alloc(NN + 1);
    int*      cursor = (int*)alloc(NN);
    int*      bsum   = (int*)alloc(NBLK);
    int*      bpre   = (int*)alloc(NBLK);
    uint4*    wfrag1 = (uint4*)alloc(8192);        // 2048 uint4 (32 KB)
    uint4*    wfrag2 = (uint4*)alloc(4096);        // 1024 uint4 (16 KB)
    size_t    binsOff = off;
    int*      bdst   = (int*)alloc((size_t)NBUCK * CAPB);        // 2.4M ints
    int2*     bse    = (int2*)alloc((size_t)NBUCK * CAPB * 2);   // 4.8M ints
    int2*     edge2  = (int2*)alloc((size_t)NE * 2);
    float*    as1    = alloc(NN * 4);
    float*    ad1    = alloc(NN * 4);
    unsigned* h1b    = (unsigned*)alloc((size_t)NN * 64);        // bf16-packed h1 [N][128]
    // xs1b overlays the bin region (bdst+bse = 7.2M words >= 6.4M; bins dead before gemm1)
    unsigned* xs1b   = (unsigned*)(wsf + binsOff);
    unsigned* xs2b   = xs1b;
    float*    as2 = as1;
    float*    ad2 = ad1;

    // zero params + deg + bcur (contiguous at ws start)
    hipMemsetAsync(d_ws, 0, (64 + 100032 + 64) * sizeof(float), stream);

    k_wprep<<<12, 256, 0, stream>>>(W1, W2, wfrag1, wfrag2);
    k_binA <<<NBINBLK, 256, 0, stream>>>(srcI, dstI, ew, bcur, bdst, bse, params);
    k_histB<<<2048, 256, 0, stream>>>(bdst, bcur, deg);
    k_scanA<<<NBLK, 256, 0, stream>>>(deg, bsum);
    k_scanB<<<1, 128, 0, stream>>>(bsum, bpre, rowptr);
    k_scanC<<<NBLK, 256, 0, stream>>>(deg, bpre, rowptr, cursor);
    k_binB <<<2048, 256, 0, stream>>>(bdst, bse, bcur, cursor, edge2);
    k_setup<<<1, 128, 0, stream>>>(We1, ae1v, We2, ae2v, params);
    k_gemm1<<<(NN + 63) / 64, 256, 0, stream>>>(x, wfrag1, as1v, ad1v, xs1b, as1, ad1);
    k_agg1 <<<25000, 256, 0, stream>>>(xs1b, as1, ad1, rowptr, edge2, params, b1, h1b);
    k_gemm2<<<(NN + 63) / 64, 256, 0, stream>>>(h1b, wfrag2, as2v, ad2v, xs2b, as2, ad2);
    k_agg2 <<<25000, 256, 0, stream>>>((const unsigned short*)xs2b, as2, ad2, rowptr, edge2, params, b2, (float*)d_out);
}